// Round 3
// baseline (24.229 us; speedup 1.0000x reference)
//
#include <hip/hip_runtime.h>

#define B_ 32
#define X_ 128
#define Y_ 256
#define C_ 64
#define BDIM 64
#define MIN_VALF -4294967295.0f

// Insert v into descending sorted triple (m1 >= m2 >= m3), keeping top-3.
__device__ __forceinline__ void insert3(float& m1, float& m2, float& m3, float v) {
    float hi1 = fmaxf(m1, v);
    float lo1 = fminf(m1, v);
    m1 = hi1;
    float hi2 = fmaxf(m2, lo1);
    float lo2 = fminf(m2, lo1);
    m2 = hi2;
    m3 = fmaxf(m3, lo2);
}

__global__ __launch_bounds__(BDIM) void topk_pool_kernel(
    const float* __restrict__ inp,
    const float* __restrict__ xmask,
    const float* __restrict__ ymask,
    float* __restrict__ out)
{
    const int lane = threadIdx.x & 63;

    // Bijective hash remap of block -> (b,x): 1997 is odd => (p*1997)&4095 is a
    // permutation of [0,4096). This scatters x positions AND b values across
    // CUs so x-masked (instant-exit) waves are spread evenly instead of
    // idling entire CUs, and 1-wave blocks let the HW scheduler rebalance
    // dynamically as blocks retire.
    const int p  = blockIdx.x;
    const int w  = (p * 1997) & (B_ * X_ - 1);
    const int b  = w >> 7;          // / X_
    const int x  = w & (X_ - 1);

    // y_len = sum(y_mask[b,:]) — prefix mask, so sum == count of valid rows.
    const float* ym = ymask + b * Y_;
    float ysum = ym[lane] + ym[lane + 64] + ym[lane + 128] + ym[lane + 192];
    #pragma unroll
    for (int off = 32; off > 0; off >>= 1) ysum += __shfl_xor(ysum, off);
    const int   ylen    = (int)(ysum + 0.5f);
    const float inv_len = 1.0f / fmaxf(ysum, 1.0f);

    const float xm = xmask[b * X_ + x];

    float* orow   = out + (size_t)w * (3 * C_);
    const int c0   = (lane & 15) << 2;   // channel base for this lane's float4
    const int yofs = lane >> 4;          // which y-subgroup (0..3)

    if (xm == 0.0f) {
        // All three outputs are exactly 0 for x-masked rows.
        if (yofs < 3)
            *reinterpret_cast<float4*>(orow + yofs * C_ + c0) =
                make_float4(0.f, 0.f, 0.f, 0.f);
        return;
    }

    // Two independent accumulator chains (A: m*/s, B: n*/r) so the unrolled
    // batch of 4 loads has short dependency chains and 4 loads in flight.
    float m1[4], m2[4], m3[4], s[4];
    float n1[4], n2[4], n3[4], r[4];
    #pragma unroll
    for (int j = 0; j < 4; ++j) {
        m1[j] = MIN_VALF; m2[j] = MIN_VALF; m3[j] = MIN_VALF; s[j] = 0.0f;
        n1[j] = MIN_VALF; n2[j] = MIN_VALF; n3[j] = MIN_VALF; r[j] = 0.0f;
    }

    const float* base = inp + (size_t)(b * X_ + x) * (Y_ * C_) + c0;
    int y = yofs;
    // Unrolled x4: rows y, y+4, y+8, y+12 — all strictly < ylen.
    for (; y + 12 < ylen; y += 16) {
        float4 v0 = *reinterpret_cast<const float4*>(base + (size_t)(y     ) * C_);
        float4 v1 = *reinterpret_cast<const float4*>(base + (size_t)(y +  4) * C_);
        float4 v2 = *reinterpret_cast<const float4*>(base + (size_t)(y +  8) * C_);
        float4 v3 = *reinterpret_cast<const float4*>(base + (size_t)(y + 12) * C_);
        float a0[4] = {v0.x, v0.y, v0.z, v0.w};
        float a1[4] = {v1.x, v1.y, v1.z, v1.w};
        float a2[4] = {v2.x, v2.y, v2.z, v2.w};
        float a3[4] = {v3.x, v3.y, v3.z, v3.w};
        #pragma unroll
        for (int j = 0; j < 4; ++j) {
            s[j] += a0[j];
            insert3(m1[j], m2[j], m3[j], a0[j]);
            r[j] += a2[j];
            insert3(n1[j], n2[j], n3[j], a2[j]);
            s[j] += a1[j];
            insert3(m1[j], m2[j], m3[j], a1[j]);
            r[j] += a3[j];
            insert3(n1[j], n2[j], n3[j], a3[j]);
        }
    }
    // Remainder (at most 3 rows per lane).
    for (; y < ylen; y += 4) {
        float4 v = *reinterpret_cast<const float4*>(base + (size_t)y * C_);
        float vv[4] = {v.x, v.y, v.z, v.w};
        #pragma unroll
        for (int j = 0; j < 4; ++j) {
            s[j] += vv[j];
            insert3(m1[j], m2[j], m3[j], vv[j]);
        }
    }
    // Merge chain B into chain A.
    #pragma unroll
    for (int j = 0; j < 4; ++j) {
        s[j] += r[j];
        insert3(m1[j], m2[j], m3[j], n1[j]);
        insert3(m1[j], m2[j], m3[j], n2[j]);
        insert3(m1[j], m2[j], m3[j], n3[j]);
    }

    // Merge the 4 y-subgroups (lanes l, l^16, l^32 hold same channels).
    #pragma unroll
    for (int step = 0; step < 2; ++step) {
        const int msk = 16 << step;
        #pragma unroll
        for (int j = 0; j < 4; ++j) {
            float o1 = __shfl_xor(m1[j], msk);
            float o2 = __shfl_xor(m2[j], msk);
            float o3 = __shfl_xor(m3[j], msk);
            float os = __shfl_xor(s[j],  msk);
            s[j] += os;
            insert3(m1[j], m2[j], m3[j], o1);
            insert3(m1[j], m2[j], m3[j], o2);
            insert3(m1[j], m2[j], m3[j], o3);
        }
    }

    // Epilogue: group 0 -> top1, group 1 -> top3-mean, group 2 -> mean-pool.
    if (yofs == 0) {
        float4 o;
        o.x = ((ylen >= 1) ? m1[0] : s[0] * inv_len) * xm;
        o.y = ((ylen >= 1) ? m1[1] : s[1] * inv_len) * xm;
        o.z = ((ylen >= 1) ? m1[2] : s[2] * inv_len) * xm;
        o.w = ((ylen >= 1) ? m1[3] : s[3] * inv_len) * xm;
        *reinterpret_cast<float4*>(orow + 0 * C_ + c0) = o;
    } else if (yofs == 1) {
        const float third = 1.0f / 3.0f;
        float4 o;
        o.x = ((ylen >= 3) ? (m1[0] + m2[0] + m3[0]) * third : s[0] * inv_len) * xm;
        o.y = ((ylen >= 3) ? (m1[1] + m2[1] + m3[1]) * third : s[1] * inv_len) * xm;
        o.z = ((ylen >= 3) ? (m1[2] + m2[2] + m3[2]) * third : s[2] * inv_len) * xm;
        o.w = ((ylen >= 3) ? (m1[3] + m2[3] + m3[3]) * third : s[3] * inv_len) * xm;
        *reinterpret_cast<float4*>(orow + 1 * C_ + c0) = o;
    } else if (yofs == 2) {
        float4 o;
        o.x = s[0] * inv_len;
        o.y = s[1] * inv_len;
        o.z = s[2] * inv_len;
        o.w = s[3] * inv_len;
        *reinterpret_cast<float4*>(orow + 2 * C_ + c0) = o;
    }
}

extern "C" void kernel_launch(void* const* d_in, const int* in_sizes, int n_in,
                              void* d_out, int out_size, void* d_ws, size_t ws_size,
                              hipStream_t stream) {
    const float* inp   = (const float*)d_in[0];
    const float* xmask = (const float*)d_in[1];
    const float* ymask = (const float*)d_in[2];
    float* out = (float*)d_out;

    const int grid = B_ * X_;   // 4096 one-wave blocks, dynamically balanced
    topk_pool_kernel<<<grid, BDIM, 0, stream>>>(inp, xmask, ymask, out);
}

// Round 4
// 20.329 us; speedup vs baseline: 1.1919x; 1.1919x over previous
//
#include <hip/hip_runtime.h>

#define B_ 32
#define X_ 128
#define Y_ 256
#define C_ 64
#define BDIM 256
#define MIN_VALF -4294967295.0f

// Insert v into descending sorted triple (m1 >= m2 >= m3), keeping top-3.
__device__ __forceinline__ void insert3(float& m1, float& m2, float& m3, float v) {
    float hi1 = fmaxf(m1, v);
    float lo1 = fminf(m1, v);
    m1 = hi1;
    float hi2 = fmaxf(m2, lo1);
    float lo2 = fminf(m2, lo1);
    m2 = hi2;
    m3 = fmaxf(m3, lo2);
}

// One block per (b,x). 4 waves, each owning a 64-row y-chunk, so per-wave
// work is bounded (<=4 unrolled iterations) regardless of ylen — kills the
// long-tail where ylen=256 waves ran 16 serial-latency iterations.
__global__ __launch_bounds__(BDIM) void topk_pool_kernel(
    const float* __restrict__ inp,
    const float* __restrict__ xmask,
    const float* __restrict__ ymask,
    float* __restrict__ out)
{
    const int tid  = threadIdx.x;
    const int lane = tid & 63;
    const int wv   = tid >> 6;                      // wave id = y-chunk, 0..3

    // Bijective scatter of block -> (b,x) to mix long/short blocks across CUs.
    const int w = (blockIdx.x * 1997) & (B_ * X_ - 1);
    const int b = w >> 7;
    const int x = w & (X_ - 1);

    __shared__ float lds[4 * 16 * 16];              // [wave][chgrp][16 floats]

    // ylen = sum(y_mask[b,:]) — prefix mask.
    const float* ym = ymask + b * Y_;
    float ysum = ym[lane] + ym[lane + 64] + ym[lane + 128] + ym[lane + 192];
    #pragma unroll
    for (int off = 32; off > 0; off >>= 1) ysum += __shfl_xor(ysum, off);
    const int   ylen    = (int)(ysum + 0.5f);
    const float inv_len = 1.0f / fmaxf(ysum, 1.0f);

    const float xm = xmask[b * X_ + x];
    float* orow = out + (size_t)w * (3 * C_);

    if (xm == 0.0f) {                               // uniform across block
        if (wv == 0) {
            orow[lane]       = 0.0f;
            orow[64 + lane]  = 0.0f;
            orow[128 + lane] = 0.0f;
        }
        return;                                     // ALL waves return: no sync hazard
    }

    const int c0   = (lane & 15) << 2;              // channel base (float4)
    const int yofs = lane >> 4;                     // y-subgroup 0..3

    float m1[4], m2[4], m3[4], s[4];
    #pragma unroll
    for (int j = 0; j < 4; ++j) {
        m1[j] = MIN_VALF; m2[j] = MIN_VALF; m3[j] = MIN_VALF; s[j] = 0.0f;
    }

    const float* base = inp + (size_t)(b * X_ + x) * (Y_ * C_) + c0;
    const int y_lo = wv * 64;
    const int y_hi = (y_lo + 64 < ylen) ? (y_lo + 64) : ylen;

    int y = y_lo + yofs;
    // Full pass: rows y, y+4, y+8, y+12 (4 loads in flight).
    for (; y + 12 < y_hi; y += 16) {
        float4 v0 = *reinterpret_cast<const float4*>(base + (size_t)(y     ) * C_);
        float4 v1 = *reinterpret_cast<const float4*>(base + (size_t)(y +  4) * C_);
        float4 v2 = *reinterpret_cast<const float4*>(base + (size_t)(y +  8) * C_);
        float4 v3 = *reinterpret_cast<const float4*>(base + (size_t)(y + 12) * C_);
        float a0[4] = {v0.x, v0.y, v0.z, v0.w};
        float a1[4] = {v1.x, v1.y, v1.z, v1.w};
        float a2[4] = {v2.x, v2.y, v2.z, v2.w};
        float a3[4] = {v3.x, v3.y, v3.z, v3.w};
        #pragma unroll
        for (int j = 0; j < 4; ++j) {
            s[j] += a0[j]; insert3(m1[j], m2[j], m3[j], a0[j]);
            s[j] += a1[j]; insert3(m1[j], m2[j], m3[j], a1[j]);
            s[j] += a2[j]; insert3(m1[j], m2[j], m3[j], a2[j]);
            s[j] += a3[j]; insert3(m1[j], m2[j], m3[j], a3[j]);
        }
    }
    // Remainder (<=3 rows for this subgroup).
    for (; y < y_hi; y += 4) {
        float4 v = *reinterpret_cast<const float4*>(base + (size_t)y * C_);
        float vv[4] = {v.x, v.y, v.z, v.w};
        #pragma unroll
        for (int j = 0; j < 4; ++j) {
            s[j] += vv[j]; insert3(m1[j], m2[j], m3[j], vv[j]);
        }
    }

    // In-wave merge of the 4 y-subgroups (after this every lane holds the
    // wave-chunk result for its 4 channels).
    #pragma unroll
    for (int step = 0; step < 2; ++step) {
        const int msk = 16 << step;
        #pragma unroll
        for (int j = 0; j < 4; ++j) {
            float o1 = __shfl_xor(m1[j], msk);
            float o2 = __shfl_xor(m2[j], msk);
            float o3 = __shfl_xor(m3[j], msk);
            float os = __shfl_xor(s[j],  msk);
            s[j] += os;
            insert3(m1[j], m2[j], m3[j], o1);
            insert3(m1[j], m2[j], m3[j], o2);
            insert3(m1[j], m2[j], m3[j], o3);
        }
    }

    // Stage per-wave partials: lds[wv][chgrp][m1[0..3] m2[0..3] m3[0..3] s[0..3]]
    if (yofs == 0) {
        float* dst = &lds[(wv * 16 + (lane & 15)) * 16];
        *reinterpret_cast<float4*>(dst +  0) = make_float4(m1[0], m1[1], m1[2], m1[3]);
        *reinterpret_cast<float4*>(dst +  4) = make_float4(m2[0], m2[1], m2[2], m2[3]);
        *reinterpret_cast<float4*>(dst +  8) = make_float4(m3[0], m3[1], m3[2], m3[3]);
        *reinterpret_cast<float4*>(dst + 12) = make_float4(s[0],  s[1],  s[2],  s[3]);
    }
    __syncthreads();

    // Wave 0 merges the 4 chunk-partials; lane == channel.
    if (wv == 0) {
        const int ch = lane, lg = ch >> 2, e = ch & 3;
        float M1 = MIN_VALF, M2 = MIN_VALF, M3 = MIN_VALF, S = 0.0f;
        #pragma unroll
        for (int q = 0; q < 4; ++q) {
            const float* src = &lds[(q * 16 + lg) * 16];
            float a = src[e], bb = src[4 + e], c = src[8 + e], d = src[12 + e];
            S += d;
            insert3(M1, M2, M3, a);
            insert3(M1, M2, M3, bb);
            insert3(M1, M2, M3, c);
        }
        const float mean = S * inv_len;
        const float top1 = ((ylen >= 1) ? M1 : mean) * xm;
        const float top3 = ((ylen >= 3) ? (M1 + M2 + M3) * (1.0f / 3.0f) : mean) * xm;
        orow[ch]       = top1;
        orow[64 + ch]  = top3;
        orow[128 + ch] = mean;          // mean_pool is NOT masked by x in ref
    }
}

extern "C" void kernel_launch(void* const* d_in, const int* in_sizes, int n_in,
                              void* d_out, int out_size, void* d_ws, size_t ws_size,
                              hipStream_t stream) {
    const float* inp   = (const float*)d_in[0];
    const float* xmask = (const float*)d_in[1];
    const float* ymask = (const float*)d_in[2];
    float* out = (float*)d_out;

    const int grid = B_ * X_;           // one block per (b,x)
    topk_pool_kernel<<<grid, BDIM, 0, stream>>>(inp, xmask, ymask, out);
}